// Round 13
// baseline (699.569 us; speedup 1.0000x reference)
//
#include <hip/hip_runtime.h>
#include <hip/hip_bf16.h>

#define NN 100000
#define EE 400000
#define GG 4096
#define DD 128
#define ATOM_DIM 101
#define BOND_DIM 11
#define EAP 12    // padded bond-feature stride (48B)
#define GEMM_GRID 512

typedef __attribute__((ext_vector_type(8))) short bf16x8;
typedef __attribute__((ext_vector_type(4))) float f32x4;
typedef __attribute__((ext_vector_type(2))) float f32x2;

__device__ __forceinline__ float b2f(short s) {
    unsigned u = ((unsigned)(unsigned short)s) << 16;
    float f; __builtin_memcpy(&f, &u, 4); return f;
}
__device__ __forceinline__ unsigned short f2b(float f) {
    unsigned u; __builtin_memcpy(&u, &f, 4);
    u += 0x7FFFu + ((u >> 16) & 1u);          // RNE
    return (unsigned short)(u >> 16);
}

// ---------------- index dtype detection (int32 vs int64), parallel ----------------
__global__ void detect64_kernel(const void* ei, int npairs, int* flag) {
    __shared__ int any;
    if (threadIdx.x == 0) any = 0;
    __syncthreads();
    const int* p = (const int*)ei;
    int v = 0;
    for (int i = threadIdx.x; i < npairs; i += blockDim.x) v |= p[2 * i + 1];
    if (v) atomicOr(&any, 1);
    __syncthreads();
    if (threadIdx.x == 0) *flag = (any == 0) ? 1 : 0;
}
__device__ __forceinline__ int getIdx(const void* p, long i, int is64) {
    if (is64) return (int)(((const long long*)p)[i]);
    return ((const int*)p)[i];
}

// ---------------- counting sort by dst ----------------
__global__ __launch_bounds__(256) void hist_kernel(
    const void* __restrict__ eidx, const int* __restrict__ flag, int* __restrict__ counts) {
    int e = blockIdx.x * 256 + threadIdx.x;
    if (e >= EE) return;
    int is64 = *flag;
    int dn = getIdx(eidx, (long)EE + e, is64);
    atomicAdd(&counts[dn], 1);
}

__global__ __launch_bounds__(256) void scan1_kernel(
    const int* __restrict__ counts, int* __restrict__ tmp, int* __restrict__ bsum, int n) {
    __shared__ int sd[256];
    const int tid = threadIdx.x;
    int i = blockIdx.x * 256 + tid;
    int v = (i < n) ? counts[i] : 0;
    sd[tid] = v; __syncthreads();
    #pragma unroll
    for (int off = 1; off < 256; off <<= 1) {
        int a = (tid >= off) ? sd[tid - off] : 0;
        __syncthreads();
        sd[tid] += a;
        __syncthreads();
    }
    if (i < n) tmp[i] = sd[tid] - v;
    if (tid == 255) bsum[blockIdx.x] = sd[255];
}

__global__ __launch_bounds__(512) void scan2_kernel(
    const int* __restrict__ bsum, int* __restrict__ bsumx, int nb) {
    __shared__ int sd[512];
    const int tid = threadIdx.x;
    int v = (tid < nb) ? bsum[tid] : 0;
    sd[tid] = v; __syncthreads();
    #pragma unroll
    for (int off = 1; off < 512; off <<= 1) {
        int a = (tid >= off) ? sd[tid - off] : 0;
        __syncthreads();
        sd[tid] += a;
        __syncthreads();
    }
    if (tid < nb) bsumx[tid] = sd[tid] - v;
}

__global__ __launch_bounds__(256) void scan3_kernel(
    const int* __restrict__ tmp, const int* __restrict__ bsumx,
    int* __restrict__ row_ptr, int n) {
    int i = blockIdx.x * 256 + threadIdx.x;
    if (i < n) row_ptr[i] = tmp[i] + bsumx[blockIdx.x];
    if (i == 0) row_ptr[n] = EE;
}

__global__ __launch_bounds__(256) void scatter_kernel(
    const void* __restrict__ eidx, const int* __restrict__ flag,
    const float* __restrict__ ea, const int* __restrict__ row_ptr,
    int* __restrict__ cursor, int* __restrict__ src_sorted, float* __restrict__ eas) {
    int e = blockIdx.x * 256 + threadIdx.x;
    if (e >= EE) return;
    int is64 = *flag;
    int dn = getIdx(eidx, (long)EE + e, is64);
    int sv = getIdx(eidx, e, is64);
    int pos = row_ptr[dn] + atomicAdd(&cursor[dn], 1);
    src_sorted[pos] = sv;
    const float* sp = ea + (long)e * BOND_DIM;
    float* dp = eas + (long)pos * EAP;
    #pragma unroll
    for (int k = 0; k < BOND_DIM; ++k) dp[k] = sp[k];
    dp[11] = 0.f;
}

// ---------------- fused transform + message + aggregate (CSR) ----------------
#define EDGE_MATH(TV, EVp, A0, A1)                                              \
    {                                                                           \
        float c0 = bbv.x, c1 = bbv.y;                                           \
        _Pragma("unroll")                                                       \
        for (int k = 0; k < BOND_DIM; ++k) {                                    \
            c0 = fmaf((EVp)[k], wk0[k], c0);                                    \
            c1 = fmaf((EVp)[k], wk1[k], c1);                                    \
        }                                                                       \
        float f0 = b2f((short)((TV) & 0xffff)), f1 = b2f((short)((TV) >> 16));  \
        if (aff) { f0 = fmaxf(f0 * sc0 + sh0, 0.f); f1 = fmaxf(f1 * sc1v + sh1v, 0.f); } \
        A0 += fmaxf(f0 + c0, 0.f);                                              \
        A1 += fmaxf(f1 + c1, 0.f);                                              \
    }

__global__ __launch_bounds__(256) void msg_csr_kernel(
    const unsigned short* __restrict__ h,    // [N][128] bf16
    const float* __restrict__ sc, const float* __restrict__ sh,
    const int* __restrict__ src_sorted, const int* __restrict__ row_ptr,
    const float* __restrict__ eas,
    const float* __restrict__ bw,   // [11][128]
    const float* __restrict__ bb,   // [128]
    unsigned short* __restrict__ sout)
{
    const int tid = threadIdx.x;
    const int wave = tid >> 6, lane = tid & 63;
    const int d0 = lane * 2;
    float wk0[BOND_DIM], wk1[BOND_DIM];
    #pragma unroll
    for (int k = 0; k < BOND_DIM; ++k) {
        f32x2 wv = *(const f32x2*)(bw + k * DD + d0);
        wk0[k] = wv.x; wk1[k] = wv.y;
    }
    f32x2 bbv = *(const f32x2*)(bb + d0);
    const bool aff = (sc != nullptr);
    float sc0 = 1.f, sc1v = 1.f, sh0 = 0.f, sh1v = 0.f;
    if (aff) { sc0 = sc[d0]; sc1v = sc[d0 + 1]; sh0 = sh[d0]; sh1v = sh[d0 + 1]; }

    for (int n0 = blockIdx.x * 4 + wave; n0 < NN; n0 += gridDim.x * 4) {
        const int n = __builtin_amdgcn_readfirstlane(n0);
        const int e0 = __builtin_amdgcn_readfirstlane(row_ptr[n]);
        const int e1 = __builtin_amdgcn_readfirstlane(row_ptr[n + 1]);
        float a0 = 0.f, a1 = 0.f;
        int e = e0;
        for (; e + 4 <= e1; e += 4) {
            const int eu = __builtin_amdgcn_readfirstlane(e);
            int sv0 = __builtin_amdgcn_readfirstlane(src_sorted[eu]);
            int sv1 = __builtin_amdgcn_readfirstlane(src_sorted[eu + 1]);
            int sv2 = __builtin_amdgcn_readfirstlane(src_sorted[eu + 2]);
            int sv3 = __builtin_amdgcn_readfirstlane(src_sorted[eu + 3]);
            unsigned tv0 = *(const unsigned*)(h + (long)sv0 * DD + d0);
            unsigned tv1 = *(const unsigned*)(h + (long)sv1 * DD + d0);
            unsigned tv2 = *(const unsigned*)(h + (long)sv2 * DD + d0);
            unsigned tv3 = *(const unsigned*)(h + (long)sv3 * DD + d0);
            const float* ep0 = eas + (long)eu * EAP;
            EDGE_MATH(tv0, ep0, a0, a1)
            EDGE_MATH(tv1, ep0 + EAP, a0, a1)
            EDGE_MATH(tv2, ep0 + 2 * EAP, a0, a1)
            EDGE_MATH(tv3, ep0 + 3 * EAP, a0, a1)
        }
        if (e + 2 <= e1) {
            const int eu = __builtin_amdgcn_readfirstlane(e);
            int sv0 = __builtin_amdgcn_readfirstlane(src_sorted[eu]);
            int sv1 = __builtin_amdgcn_readfirstlane(src_sorted[eu + 1]);
            unsigned tv0 = *(const unsigned*)(h + (long)sv0 * DD + d0);
            unsigned tv1 = *(const unsigned*)(h + (long)sv1 * DD + d0);
            const float* ep0 = eas + (long)eu * EAP;
            EDGE_MATH(tv0, ep0, a0, a1)
            EDGE_MATH(tv1, ep0 + EAP, a0, a1)
            e += 2;
        }
        if (e < e1) {
            const int eu = __builtin_amdgcn_readfirstlane(e);
            int sv = __builtin_amdgcn_readfirstlane(src_sorted[eu]);
            unsigned tv = *(const unsigned*)(h + (long)sv * DD + d0);
            const float* ep0 = eas + (long)eu * EAP;
            EDGE_MATH(tv, ep0, a0, a1)
        }
        unsigned tn = *(const unsigned*)(h + (long)n * DD + d0);
        float t0 = b2f((short)(tn & 0xffff)), t1 = b2f((short)(tn >> 16));
        if (aff) {
            t0 = fmaxf(t0 * sc0 + sh0, 0.f); t1 = fmaxf(t1 * sc1v + sh1v, 0.f);
        }
        unsigned pk = (unsigned)f2b(t0 + a0) | ((unsigned)f2b(t1 + a1) << 16);
        *(unsigned*)(sout + (long)n * DD + d0) = pk;
    }
}

// ---------------- all weight pre-packs in one kernel ----------------
// segments: emb (2048 units), W1 x3 (4096 each), W2 x3 (4096 each); unit = 64 lanes x 8 elems
__global__ __launch_bounds__(256) void pack_all(
    const float* __restrict__ embW, const float* __restrict__ W1, const float* __restrict__ W2,
    unsigned short* __restrict__ embWf, unsigned short* __restrict__ W1f, unsigned short* __restrict__ W2f)
{
    int idx = blockIdx.x * 256 + threadIdx.x;
    const float* W; unsigned short* Wf; int Kact, N, base;
    if (idx < 2048) {
        W = embW; Wf = embWf; Kact = ATOM_DIM; N = 128; base = idx;
    } else if (idx < 2048 + 3 * 4096) {
        int r = idx - 2048; int i = r / 4096; base = r % 4096;
        W = W1 + (long)i * 128 * 256; Wf = W1f + (long)i * 4096 * 8;
        Kact = 128; N = 256;
    } else if (idx < 2048 + 6 * 4096) {
        int r = idx - 2048 - 3 * 4096; int i = r / 4096; base = r % 4096;
        W = W2 + (long)i * 256 * 128; Wf = W2f + (long)i * 4096 * 8;
        Kact = 256; N = 128;
    } else return;
    int l = base & 63;
    int NF = N >> 4;
    int f = (base >> 6) % NF;
    int ks = base / (64 * NF);
    int col = f * 16 + (l & 15);
    int k0 = ks * 32 + (l >> 4) * 8;
    bf16x8 v;
    #pragma unroll
    for (int j = 0; j < 8; ++j) {
        int k = k0 + j;
        v[j] = (k < Kact) ? (short)f2b(W[(long)k * N + col]) : (short)0;
    }
    *(bf16x8*)(Wf + (long)base * 8) = v;
}

// ---------------- A-fragment loader ----------------
template<int MODE, int KSTEPS, int KACT>
__device__ __forceinline__ void loadA(const void* Ap, long rc, int kg, bf16x8* dst) {
    if (MODE == 1) {
        const float* ap = (const float*)Ap + rc * KACT;
        #pragma unroll
        for (int ks = 0; ks < KSTEPS; ++ks) {
            bf16x8 a;
            #pragma unroll
            for (int j = 0; j < 8; ++j) {
                int gk = ks * 32 + kg + j;
                a[j] = (gk < KACT) ? (short)f2b(ap[gk]) : (short)0;
            }
            dst[ks] = a;
        }
    } else {
        const unsigned short* ap = (const unsigned short*)Ap + rc * (KSTEPS * 32) + kg;
        #pragma unroll
        for (int ks = 0; ks < KSTEPS; ++ks) dst[ks] = *(const bf16x8*)(ap + ks * 32);
    }
}

// ---------------- register-resident-B MFMA GEMM + fused BN finalize ----------------
// MODE 0: A bf16.  MODE 1: A f32 zero-padded (KACT cols).  MODE 2: bf16 relu(A*sc+sh).
// STATS: per-block partials + last-block computes sc_out/sh_out (device counter `done`).
template<int NF, int KSTEPS, int NHALVES, int MODE, bool OUT_BF16, bool STATS, int KACT = 0>
__global__ __launch_bounds__(256, 2) void gemm_reg(
    const void* __restrict__ Ap,
    const float* __restrict__ sc, const float* __restrict__ sh,
    const unsigned short* __restrict__ Wf,  // packed [KSTEPS][NFtot][64][8]
    const float* __restrict__ bias,         // [NFtot*16]
    void* __restrict__ outp,
    float* __restrict__ partial,            // [GEMM_GRID][2*NF*16]
    const float* __restrict__ gamma, const float* __restrict__ beta,
    float* __restrict__ sc_out, float* __restrict__ sh_out,
    int* __restrict__ done,
    int M)
{
    constexpr int K = KSTEPS * 32;
    constexpr int NCb = NF * 16;
    constexpr int NFtot = NF * NHALVES;
    constexpr int NCtot = NCb * NHALVES;
    constexpr int ESZ = OUT_BF16 ? 2 : 4;
    constexpr int RSTRIDE = NCb + (OUT_BF16 ? 8 : 4);
    constexpr int ROWBYTES = NCb * ESZ;
    constexpr int CHUNKS = 64 * ROWBYTES / 16;
    constexpr int CPR = ROWBYTES / 16;

    __shared__ __align__(16) char sOut[2][64 * RSTRIDE * ESZ];
    __shared__ float s_sc[(MODE == 2) ? K : 1];
    __shared__ float s_sh[(MODE == 2) ? K : 1];
    __shared__ float s_ps[STATS ? 2 * NCb : 1];
    __shared__ int amLast;

    const int tid = threadIdx.x;
    const int wave = tid >> 6, l = tid & 63;
    const int kg = (l >> 4) * 8;

    int half, mt;
    if (NHALVES == 2) {
        int b = blockIdx.x;
        half = (b >> 3) & 1;
        mt = (b & 7) | ((b >> 4) << 3);
    } else {
        half = 0; mt = blockIdx.x;
    }
    const int col0 = half * NCb;
    const int bstep = gridDim.x / NHALVES;

    if (MODE == 2 || STATS) {
        if (MODE == 2) {
            for (int i = tid; i < K; i += 256) { s_sc[i] = sc[i]; s_sh[i] = sh[i]; }
        }
        if (STATS) {
            for (int i = tid; i < 2 * NCb; i += 256) s_ps[i] = 0.f;
        }
        __syncthreads();
    }

    // B panel resident in registers
    bf16x8 bfr[KSTEPS][NF];
    {
        const bf16x8* wp = (const bf16x8*)Wf;
        #pragma unroll
        for (int ks = 0; ks < KSTEPS; ++ks)
            #pragma unroll
            for (int f = 0; f < NF; ++f)
                bfr[ks][f] = wp[((long)ks * NFtot + half * NF + f) * 64 + l];
    }

    float bb[NF];
    #pragma unroll
    for (int f = 0; f < NF; ++f) bb[f] = bias[col0 + f * 16 + (l & 15)];

    float ssum[NF], ssq[NF];
    #pragma unroll
    for (int f = 0; f < NF; ++f) { ssum[f] = 0.f; ssq[f] = 0.f; }

    const int MT = (M + 63) >> 6;

    bf16x8 ldA[KSTEPS], ldB[KSTEPS];
    {
        int rr = mt * 64 + wave * 16 + (l & 15);
        int rc = rr < M ? rr : M - 1;
        loadA<MODE, KSTEPS, KACT>(Ap, rc, kg, ldA);
    }

    int pbuf = 0;
    for (; mt < MT; mt += bstep) {
        const int nxt = mt + bstep;
        if (nxt < MT) {
            int rr = nxt * 64 + wave * 16 + (l & 15);
            int rc = rr < M ? rr : M - 1;
            loadA<MODE, KSTEPS, KACT>(Ap, rc, kg, ldB);
        }

        if (MODE == 2) {
            #pragma unroll
            for (int ks = 0; ks < KSTEPS; ++ks) {
                f32x4 s0 = *(const f32x4*)&s_sc[ks * 32 + kg];
                f32x4 s1 = *(const f32x4*)&s_sc[ks * 32 + kg + 4];
                f32x4 h0 = *(const f32x4*)&s_sh[ks * 32 + kg];
                f32x4 h1 = *(const f32x4*)&s_sh[ks * 32 + kg + 4];
                float sv[8] = {s0.x, s0.y, s0.z, s0.w, s1.x, s1.y, s1.z, s1.w};
                float hv[8] = {h0.x, h0.y, h0.z, h0.w, h1.x, h1.y, h1.z, h1.w};
                #pragma unroll
                for (int j = 0; j < 8; ++j) {
                    float v = fmaxf(b2f(ldA[ks][j]) * sv[j] + hv[j], 0.f);
                    ldA[ks][j] = (short)f2b(v);
                }
            }
        }

        f32x4 acc[NF];
        #pragma unroll
        for (int f = 0; f < NF; ++f) acc[f] = (f32x4){0.f, 0.f, 0.f, 0.f};
        #pragma unroll
        for (int ks = 0; ks < KSTEPS; ++ks)
            #pragma unroll
            for (int f = 0; f < NF; ++f)
                acc[f] = __builtin_amdgcn_mfma_f32_16x16x32_bf16(ldA[ks], bfr[ks][f], acc[f], 0, 0, 0);

        const int rtile = mt * 64;
        char* sb = sOut[pbuf];
        #pragma unroll
        for (int f = 0; f < NF; ++f) {
            const int cl = f * 16 + (l & 15);
            #pragma unroll
            for (int j = 0; j < 4; ++j) {
                const int rl = wave * 16 + (l >> 4) * 4 + j;
                float v = acc[f][j] + bb[f];
                if (OUT_BF16) ((unsigned short*)sb)[rl * RSTRIDE + cl] = f2b(v);
                else          ((float*)sb)[rl * RSTRIDE + cl] = v;
                if (STATS && rtile + rl < M) { ssum[f] += v; ssq[f] += v * v; }
            }
        }
        __syncthreads();

        const int rmax = M - rtile;
        #pragma unroll
        for (int i = 0; i < CHUNKS / 256; ++i) {
            int c = i * 256 + tid;
            int row = c / CPR;
            int off = (c % CPR) * 16;
            if (row < rmax) {
                f32x4 v = *(const f32x4*)(sb + row * (RSTRIDE * ESZ) + off);
                char* gp = (char*)outp + ((long)(rtile + row) * NCtot + col0) * ESZ + off;
                *(f32x4*)gp = v;
            }
        }
        pbuf ^= 1;

        #pragma unroll
        for (int ks = 0; ks < KSTEPS; ++ks) ldA[ks] = ldB[ks];
    }

    if (STATS) {
        #pragma unroll
        for (int f = 0; f < NF; ++f) {
            float s = ssum[f], q = ssq[f];
            s += __shfl_xor(s, 16); s += __shfl_xor(s, 32);
            q += __shfl_xor(q, 16); q += __shfl_xor(q, 32);
            if (l < 16) {
                atomicAdd(&s_ps[f * 16 + l], s);
                atomicAdd(&s_ps[NCb + f * 16 + l], q);
            }
        }
        __syncthreads();
        float* pb = partial + (long)blockIdx.x * 2 * NCb;
        for (int i = tid; i < 2 * NCb; i += 256)
            __hip_atomic_store(&pb[i], s_ps[i], __ATOMIC_RELAXED, __HIP_MEMORY_SCOPE_AGENT);
        __threadfence();
        __syncthreads();
        if (tid == 0) {
            int prev = atomicAdd(done, 1);
            amLast = (prev == (int)gridDim.x - 1);
        }
        __syncthreads();
        if (amLast) {
            __threadfence();
            const float invN = 1.f / (float)M;
            for (int c = tid; c < NCtot; c += 256) {
                const int hh = c / NCb, cl = c % NCb;
                float s = 0.f, q = 0.f;
                const int nrel = (NHALVES == 2) ? (GEMM_GRID / 2) : GEMM_GRID;
                #pragma unroll 8
                for (int j = 0; j < nrel; ++j) {
                    int b = (NHALVES == 2) ? (((j >> 3) << 4) | (hh << 3) | (j & 7)) : j;
                    const float* pb2 = partial + (long)b * 2 * NCb;
                    s += __hip_atomic_load(&pb2[cl], __ATOMIC_RELAXED, __HIP_MEMORY_SCOPE_AGENT);
                    q += __hip_atomic_load(&pb2[NCb + cl], __ATOMIC_RELAXED, __HIP_MEMORY_SCOPE_AGENT);
                }
                float m = s * invN;
                float v = q * invN - m * m;
                float g = gamma[c] * rsqrtf(v + 1e-5f);
                sc_out[c] = g;
                sh_out[c] = beta[c] - m * g;
            }
            if (tid == 0) *done = 0;   // replay-safe reset
        }
    }
}

// ---------------- pooling (bf16 h, 2 ch/lane dword loads) ----------------
__global__ __launch_bounds__(64) void pool_kernel(
    const unsigned short* __restrict__ h,
    const float* __restrict__ sc, const float* __restrict__ sh,
    const void* __restrict__ batchp, const int* __restrict__ flag,
    int Nn, float* __restrict__ out)
{
    const int g = blockIdx.x;
    const int t = threadIdx.x;
    const int d0 = t * 2;
    const int is64 = *flag;
    int lo = 0, hi = Nn;
    while (lo < hi) { int mid = (lo + hi) >> 1; if (getIdx(batchp, mid, is64) < g) lo = mid + 1; else hi = mid; }
    const int s0 = lo;
    hi = Nn;
    while (lo < hi) { int mid = (lo + hi) >> 1; if (getIdx(batchp, mid, is64) < g + 1) lo = mid + 1; else hi = mid; }
    const int s1 = lo;
    float a0 = 0.f, a1 = 0.f;
    for (int r = s0; r < s1; ++r) {
        unsigned v = *(const unsigned*)(h + (long)r * DD + d0);
        a0 += b2f((short)(v & 0xffff));
        a1 += b2f((short)(v >> 16));
    }
    const int cnt = s1 - s0;
    f32x2 o; o.x = 0.f; o.y = 0.f;
    if (cnt > 0) {
        float inv = 1.f / (float)cnt;
        o.x = a0 * inv * sc[d0] + sh[d0];
        o.y = a1 * inv * sc[d0 + 1] + sh[d0 + 1];
    }
    *(f32x2*)(out + (long)g * DD + d0) = o;
}

// ---------------- launch ----------------
extern "C" void kernel_launch(void* const* d_in, const int* in_sizes, int n_in,
                              void* d_out, int out_size, void* d_ws, size_t ws_size,
                              hipStream_t stream)
{
    const float* x     = (const float*)d_in[0];
    const float* ea    = (const float*)d_in[1];
    const float* embW  = (const float*)d_in[2];
    const float* embB  = (const float*)d_in[3];
    const float* bondW = (const float*)d_in[4];
    const float* bondB = (const float*)d_in[5];
    const float* W1    = (const float*)d_in[6];
    const float* b1    = (const float*)d_in[7];
    const float* g1    = (const float*)d_in[8];
    const float* be1   = (const float*)d_in[9];
    const float* W2    = (const float*)d_in[10];
    const float* b2    = (const float*)d_in[11];
    const float* gout  = (const float*)d_in[12];
    const float* bout  = (const float*)d_in[13];
    const void*  eidx  = d_in[14];
    const void*  batch = d_in[15];
    float* out = (float*)d_out;

    char* w = (char*)d_ws;
    unsigned short* h   = (unsigned short*)w;   w += (long)NN * DD * 2;        // 25.6MB
    unsigned short* s   = (unsigned short*)w;   w += (long)NN * DD * 2;        // 25.6MB
    unsigned short* z1  = (unsigned short*)w;   w += (long)NN * 256 * 2;       // 51.2MB
    float* eas  = (float*)w;                    w += (long)EE * EAP * 4;       // 19.2MB
    int* src_sorted = (int*)w;                  w += (long)EE * 4;             // 1.6MB
    int* row_ptr    = (int*)w;                  w += (long)(NN + 1) * 4;
    int* counts     = (int*)w;                  w += (long)NN * 4;   // zeroed together:
    int* cursor     = (int*)w;                  w += (long)NN * 4;   // [counts|cursor|done]
    int* done       = (int*)w;                  w += 16 * 4;
    int* tmp        = (int*)w;                  w += (long)NN * 4;
    int* bsum       = (int*)w;                  w += 1024 * 4;
    int* bsumx      = (int*)w;                  w += 1024 * 4;
    float* partial  = (float*)w;                w += (long)GEMM_GRID * 512 * 4; // 1MB
    float* sc1  = (float*)w;                    w += 256 * 4;
    float* sh1  = (float*)w;                    w += 256 * 4;
    float* sc2  = (float*)w;                    w += 128 * 4;
    float* sh2  = (float*)w;                    w += 128 * 4;
    unsigned short* embWf = (unsigned short*)w; w += 4 * 8  * 64 * 8 * 2;
    unsigned short* W1f   = (unsigned short*)w; w += 3L * 4 * 16 * 64 * 8 * 2;
    unsigned short* W2f   = (unsigned short*)w; w += 3L * 8 * 8  * 64 * 8 * 2;
    int* flag = (int*)w;

    // one memset covers counts + cursor + done
    hipMemsetAsync(counts, 0, ((size_t)2 * NN + 16) * 4, stream);

    detect64_kernel<<<1, 256, 0, stream>>>(eidx, 256, flag);
    pack_all<<<(2048 + 6 * 4096 + 255) / 256, 256, 0, stream>>>(embW, W1, W2, embWf, W1f, W2f);

    // counting sort of edges by dst -> CSR
    const int eblocks = (EE + 255) / 256;
    const int nb = (NN + 255) / 256;
    hist_kernel<<<eblocks, 256, 0, stream>>>(eidx, flag, counts);
    scan1_kernel<<<nb, 256, 0, stream>>>(counts, tmp, bsum, NN);
    scan2_kernel<<<1, 512, 0, stream>>>(bsum, bsumx, nb);
    scan3_kernel<<<nb, 256, 0, stream>>>(tmp, bsumx, row_ptr, NN);
    scatter_kernel<<<eblocks, 256, 0, stream>>>(eidx, flag, ea, row_ptr, cursor, src_sorted, eas);

    // h0 = bf16(x @ embW + embB)   (f32 x read directly, zero-padded to K=128)
    gemm_reg<8, 4, 1, 1, true, false, ATOM_DIM><<<GEMM_GRID, 256, 0, stream>>>(
        x, nullptr, nullptr, embWf, embB, h, nullptr,
        nullptr, nullptr, nullptr, nullptr, nullptr, NN);

    const float* scin = nullptr;
    const float* shin = nullptr;

    for (int i = 0; i < 3; ++i) {
        // s = bf16( t + sum relu(t[src] + bond) ),  t = bn_relu(h) applied inline
        msg_csr_kernel<<<4096, 256, 0, stream>>>(
            h, scin, shin, src_sorted, row_ptr, eas,
            bondW + (long)i * BOND_DIM * DD, bondB + (long)i * DD, s);

        // z1 = s @ W1 + b1   (bf16 out; last block computes sc1/sh1)
        gemm_reg<8, 4, 2, 0, true, true><<<GEMM_GRID, 256, 0, stream>>>(
            s, nullptr, nullptr, W1f + (long)i * 4 * 16 * 64 * 8,
            b1 + (long)i * 256, z1, partial,
            g1 + (long)i * 256, be1 + (long)i * 256, sc1, sh1, done, NN);

        // h = bf16(relu(bn(z1)) @ W2 + b2)   (last block computes sc2/sh2)
        gemm_reg<4, 8, 2, 2, true, true><<<GEMM_GRID, 256, 0, stream>>>(
            z1, sc1, sh1, W2f + (long)i * 8 * 8 * 64 * 8,
            b2 + (long)i * DD, h, partial,
            gout + (long)i * DD, bout + (long)i * DD, sc2, sh2, done, NN);

        scin = sc2; shin = sh2;
    }

    pool_kernel<<<GG, 64, 0, stream>>>(h, sc2, sh2, batch, flag, NN, out);
}

// Round 14
// 420.584 us; speedup vs baseline: 1.6633x; 1.6633x over previous
//
#include <hip/hip_runtime.h>
#include <hip/hip_bf16.h>

#define NN 100000
#define EE 400000
#define GG 4096
#define DD 128
#define ATOM_DIM 101
#define BOND_DIM 11
#define EAP 12    // padded bond-feature stride (48B)
#define GEMM_GRID 512

typedef __attribute__((ext_vector_type(8))) short bf16x8;
typedef __attribute__((ext_vector_type(4))) float f32x4;
typedef __attribute__((ext_vector_type(2))) float f32x2;

__device__ __forceinline__ float b2f(short s) {
    unsigned u = ((unsigned)(unsigned short)s) << 16;
    float f; __builtin_memcpy(&f, &u, 4); return f;
}
__device__ __forceinline__ unsigned short f2b(float f) {
    unsigned u; __builtin_memcpy(&u, &f, 4);
    u += 0x7FFFu + ((u >> 16) & 1u);          // RNE
    return (unsigned short)(u >> 16);
}

// ---------------- index dtype detection (int32 vs int64), parallel ----------------
__global__ void detect64_kernel(const void* ei, int npairs, int* flag) {
    __shared__ int any;
    if (threadIdx.x == 0) any = 0;
    __syncthreads();
    const int* p = (const int*)ei;
    int v = 0;
    for (int i = threadIdx.x; i < npairs; i += blockDim.x) v |= p[2 * i + 1];
    if (v) atomicOr(&any, 1);
    __syncthreads();
    if (threadIdx.x == 0) *flag = (any == 0) ? 1 : 0;
}
__device__ __forceinline__ int getIdx(const void* p, long i, int is64) {
    if (is64) return (int)(((const long long*)p)[i]);
    return ((const int*)p)[i];
}

// ---------------- counting sort by dst ----------------
__global__ __launch_bounds__(256) void hist_kernel(
    const void* __restrict__ eidx, const int* __restrict__ flag, int* __restrict__ counts) {
    int e = blockIdx.x * 256 + threadIdx.x;
    if (e >= EE) return;
    int is64 = *flag;
    int dn = getIdx(eidx, (long)EE + e, is64);
    atomicAdd(&counts[dn], 1);
}

__global__ __launch_bounds__(256) void scan1_kernel(
    const int* __restrict__ counts, int* __restrict__ tmp, int* __restrict__ bsum, int n) {
    __shared__ int sd[256];
    const int tid = threadIdx.x;
    int i = blockIdx.x * 256 + tid;
    int v = (i < n) ? counts[i] : 0;
    sd[tid] = v; __syncthreads();
    #pragma unroll
    for (int off = 1; off < 256; off <<= 1) {
        int a = (tid >= off) ? sd[tid - off] : 0;
        __syncthreads();
        sd[tid] += a;
        __syncthreads();
    }
    if (i < n) tmp[i] = sd[tid] - v;
    if (tid == 255) bsum[blockIdx.x] = sd[255];
}

__global__ __launch_bounds__(512) void scan2_kernel(
    const int* __restrict__ bsum, int* __restrict__ bsumx, int nb) {
    __shared__ int sd[512];
    const int tid = threadIdx.x;
    int v = (tid < nb) ? bsum[tid] : 0;
    sd[tid] = v; __syncthreads();
    #pragma unroll
    for (int off = 1; off < 512; off <<= 1) {
        int a = (tid >= off) ? sd[tid - off] : 0;
        __syncthreads();
        sd[tid] += a;
        __syncthreads();
    }
    if (tid < nb) bsumx[tid] = sd[tid] - v;
}

__global__ __launch_bounds__(256) void scan3_kernel(
    const int* __restrict__ tmp, const int* __restrict__ bsumx,
    int* __restrict__ row_ptr, int n) {
    int i = blockIdx.x * 256 + threadIdx.x;
    if (i < n) row_ptr[i] = tmp[i] + bsumx[blockIdx.x];
    if (i == 0) row_ptr[n] = EE;
}

__global__ __launch_bounds__(256) void scatter_kernel(
    const void* __restrict__ eidx, const int* __restrict__ flag,
    const float* __restrict__ ea, const int* __restrict__ row_ptr,
    int* __restrict__ cursor, int* __restrict__ src_sorted, float* __restrict__ eas) {
    int e = blockIdx.x * 256 + threadIdx.x;
    if (e >= EE) return;
    int is64 = *flag;
    int dn = getIdx(eidx, (long)EE + e, is64);
    int sv = getIdx(eidx, e, is64);
    int pos = row_ptr[dn] + atomicAdd(&cursor[dn], 1);
    src_sorted[pos] = sv;
    const float* sp = ea + (long)e * BOND_DIM;
    float* dp = eas + (long)pos * EAP;
    #pragma unroll
    for (int k = 0; k < BOND_DIM; ++k) dp[k] = sp[k];
    dp[11] = 0.f;
}

// ---------------- fused transform + message + aggregate (CSR) ----------------
#define EDGE_MATH(TV, EVp, A0, A1)                                              \
    {                                                                           \
        float c0 = bbv.x, c1 = bbv.y;                                           \
        _Pragma("unroll")                                                       \
        for (int k = 0; k < BOND_DIM; ++k) {                                    \
            c0 = fmaf((EVp)[k], wk0[k], c0);                                    \
            c1 = fmaf((EVp)[k], wk1[k], c1);                                    \
        }                                                                       \
        float f0 = b2f((short)((TV) & 0xffff)), f1 = b2f((short)((TV) >> 16));  \
        if (aff) { f0 = fmaxf(f0 * sc0 + sh0, 0.f); f1 = fmaxf(f1 * sc1v + sh1v, 0.f); } \
        A0 += fmaxf(f0 + c0, 0.f);                                              \
        A1 += fmaxf(f1 + c1, 0.f);                                              \
    }

__global__ __launch_bounds__(256) void msg_csr_kernel(
    const unsigned short* __restrict__ h,    // [N][128] bf16
    const float* __restrict__ sc, const float* __restrict__ sh,
    const int* __restrict__ src_sorted, const int* __restrict__ row_ptr,
    const float* __restrict__ eas,
    const float* __restrict__ bw,   // [11][128]
    const float* __restrict__ bb,   // [128]
    unsigned short* __restrict__ sout)
{
    const int tid = threadIdx.x;
    const int wave = tid >> 6, lane = tid & 63;
    const int d0 = lane * 2;
    float wk0[BOND_DIM], wk1[BOND_DIM];
    #pragma unroll
    for (int k = 0; k < BOND_DIM; ++k) {
        f32x2 wv = *(const f32x2*)(bw + k * DD + d0);
        wk0[k] = wv.x; wk1[k] = wv.y;
    }
    f32x2 bbv = *(const f32x2*)(bb + d0);
    const bool aff = (sc != nullptr);
    float sc0 = 1.f, sc1v = 1.f, sh0 = 0.f, sh1v = 0.f;
    if (aff) { sc0 = sc[d0]; sc1v = sc[d0 + 1]; sh0 = sh[d0]; sh1v = sh[d0 + 1]; }

    for (int n0 = blockIdx.x * 4 + wave; n0 < NN; n0 += gridDim.x * 4) {
        const int n = __builtin_amdgcn_readfirstlane(n0);
        const int e0 = __builtin_amdgcn_readfirstlane(row_ptr[n]);
        const int e1 = __builtin_amdgcn_readfirstlane(row_ptr[n + 1]);
        float a0 = 0.f, a1 = 0.f;
        int e = e0;
        for (; e + 4 <= e1; e += 4) {
            const int eu = __builtin_amdgcn_readfirstlane(e);
            int sv0 = __builtin_amdgcn_readfirstlane(src_sorted[eu]);
            int sv1 = __builtin_amdgcn_readfirstlane(src_sorted[eu + 1]);
            int sv2 = __builtin_amdgcn_readfirstlane(src_sorted[eu + 2]);
            int sv3 = __builtin_amdgcn_readfirstlane(src_sorted[eu + 3]);
            unsigned tv0 = *(const unsigned*)(h + (long)sv0 * DD + d0);
            unsigned tv1 = *(const unsigned*)(h + (long)sv1 * DD + d0);
            unsigned tv2 = *(const unsigned*)(h + (long)sv2 * DD + d0);
            unsigned tv3 = *(const unsigned*)(h + (long)sv3 * DD + d0);
            const float* ep0 = eas + (long)eu * EAP;
            EDGE_MATH(tv0, ep0, a0, a1)
            EDGE_MATH(tv1, ep0 + EAP, a0, a1)
            EDGE_MATH(tv2, ep0 + 2 * EAP, a0, a1)
            EDGE_MATH(tv3, ep0 + 3 * EAP, a0, a1)
        }
        if (e + 2 <= e1) {
            const int eu = __builtin_amdgcn_readfirstlane(e);
            int sv0 = __builtin_amdgcn_readfirstlane(src_sorted[eu]);
            int sv1 = __builtin_amdgcn_readfirstlane(src_sorted[eu + 1]);
            unsigned tv0 = *(const unsigned*)(h + (long)sv0 * DD + d0);
            unsigned tv1 = *(const unsigned*)(h + (long)sv1 * DD + d0);
            const float* ep0 = eas + (long)eu * EAP;
            EDGE_MATH(tv0, ep0, a0, a1)
            EDGE_MATH(tv1, ep0 + EAP, a0, a1)
            e += 2;
        }
        if (e < e1) {
            const int eu = __builtin_amdgcn_readfirstlane(e);
            int sv = __builtin_amdgcn_readfirstlane(src_sorted[eu]);
            unsigned tv = *(const unsigned*)(h + (long)sv * DD + d0);
            const float* ep0 = eas + (long)eu * EAP;
            EDGE_MATH(tv, ep0, a0, a1)
        }
        unsigned tn = *(const unsigned*)(h + (long)n * DD + d0);
        float t0 = b2f((short)(tn & 0xffff)), t1 = b2f((short)(tn >> 16));
        if (aff) {
            t0 = fmaxf(t0 * sc0 + sh0, 0.f); t1 = fmaxf(t1 * sc1v + sh1v, 0.f);
        }
        unsigned pk = (unsigned)f2b(t0 + a0) | ((unsigned)f2b(t1 + a1) << 16);
        *(unsigned*)(sout + (long)n * DD + d0) = pk;
    }
}

// ---------------- all weight pre-packs in one kernel ----------------
__global__ __launch_bounds__(256) void pack_all(
    const float* __restrict__ embW, const float* __restrict__ W1, const float* __restrict__ W2,
    unsigned short* __restrict__ embWf, unsigned short* __restrict__ W1f, unsigned short* __restrict__ W2f)
{
    int idx = blockIdx.x * 256 + threadIdx.x;
    const float* W; unsigned short* Wf; int Kact, N, base;
    if (idx < 2048) {
        W = embW; Wf = embWf; Kact = ATOM_DIM; N = 128; base = idx;
    } else if (idx < 2048 + 3 * 4096) {
        int r = idx - 2048; int i = r / 4096; base = r % 4096;
        W = W1 + (long)i * 128 * 256; Wf = W1f + (long)i * 4096 * 8;
        Kact = 128; N = 256;
    } else if (idx < 2048 + 6 * 4096) {
        int r = idx - 2048 - 3 * 4096; int i = r / 4096; base = r % 4096;
        W = W2 + (long)i * 256 * 128; Wf = W2f + (long)i * 4096 * 8;
        Kact = 256; N = 128;
    } else return;
    int l = base & 63;
    int NF = N >> 4;
    int f = (base >> 6) % NF;
    int ks = base / (64 * NF);
    int col = f * 16 + (l & 15);
    int k0 = ks * 32 + (l >> 4) * 8;
    bf16x8 v;
    #pragma unroll
    for (int j = 0; j < 8; ++j) {
        int k = k0 + j;
        v[j] = (k < Kact) ? (short)f2b(W[(long)k * N + col]) : (short)0;
    }
    *(bf16x8*)(Wf + (long)base * 8) = v;
}

// ---------------- A-fragment loader ----------------
template<int MODE, int KSTEPS, int KACT>
__device__ __forceinline__ void loadA(const void* Ap, long rc, int kg, bf16x8* dst) {
    if (MODE == 1) {
        const float* ap = (const float*)Ap + rc * KACT;
        #pragma unroll
        for (int ks = 0; ks < KSTEPS; ++ks) {
            bf16x8 a;
            #pragma unroll
            for (int j = 0; j < 8; ++j) {
                int gk = ks * 32 + kg + j;
                a[j] = (gk < KACT) ? (short)f2b(ap[gk]) : (short)0;
            }
            dst[ks] = a;
        }
    } else {
        const unsigned short* ap = (const unsigned short*)Ap + rc * (KSTEPS * 32) + kg;
        #pragma unroll
        for (int ks = 0; ks < KSTEPS; ++ks) dst[ks] = *(const bf16x8*)(ap + ks * 32);
    }
}

// ---------------- register-resident-B MFMA GEMM ----------------
// XCD-paired halves + double-buffered LDS store epilogue (1 barrier/tile)
// MODE 0: A bf16.  MODE 1: A f32 zero-padded (KACT cols).  MODE 2: bf16 relu(A*sc+sh).
template<int NF, int KSTEPS, int NHALVES, int MODE, bool OUT_BF16, bool STATS, int KACT = 0>
__global__ __launch_bounds__(256, 2) void gemm_reg(
    const void* __restrict__ Ap,
    const float* __restrict__ sc, const float* __restrict__ sh,
    const unsigned short* __restrict__ Wf,  // packed [KSTEPS][NFtot][64][8]
    const float* __restrict__ bias,         // [NFtot*16]
    void* __restrict__ outp,
    float* __restrict__ partial,            // [GEMM_GRID][2*NF*16]
    int M)
{
    constexpr int K = KSTEPS * 32;
    constexpr int NCb = NF * 16;
    constexpr int NFtot = NF * NHALVES;
    constexpr int NCtot = NCb * NHALVES;
    constexpr int ESZ = OUT_BF16 ? 2 : 4;
    constexpr int RSTRIDE = NCb + (OUT_BF16 ? 8 : 4);
    constexpr int ROWBYTES = NCb * ESZ;
    constexpr int CHUNKS = 64 * ROWBYTES / 16;
    constexpr int CPR = ROWBYTES / 16;

    __shared__ __align__(16) char sOut[2][64 * RSTRIDE * ESZ];
    __shared__ float s_sc[(MODE == 2) ? K : 1];
    __shared__ float s_sh[(MODE == 2) ? K : 1];
    __shared__ float s_ps[STATS ? 2 * NCb : 1];

    const int tid = threadIdx.x;
    const int wave = tid >> 6, l = tid & 63;
    const int kg = (l >> 4) * 8;

    int half, mt;
    if (NHALVES == 2) {
        int b = blockIdx.x;
        half = (b >> 3) & 1;
        mt = (b & 7) | ((b >> 4) << 3);
    } else {
        half = 0; mt = blockIdx.x;
    }
    const int col0 = half * NCb;
    const int bstep = gridDim.x / NHALVES;

    if (MODE == 2 || STATS) {
        if (MODE == 2) {
            for (int i = tid; i < K; i += 256) { s_sc[i] = sc[i]; s_sh[i] = sh[i]; }
        }
        if (STATS) {
            for (int i = tid; i < 2 * NCb; i += 256) s_ps[i] = 0.f;
        }
        __syncthreads();
    }

    // B panel resident in registers
    bf16x8 bfr[KSTEPS][NF];
    {
        const bf16x8* wp = (const bf16x8*)Wf;
        #pragma unroll
        for (int ks = 0; ks < KSTEPS; ++ks)
            #pragma unroll
            for (int f = 0; f < NF; ++f)
                bfr[ks][f] = wp[((long)ks * NFtot + half * NF + f) * 64 + l];
    }

    float bb[NF];
    #pragma unroll
    for (int f = 0; f < NF; ++f) bb[f] = bias[col0 + f * 16 + (l & 15)];

    float ssum[NF], ssq[NF];
    #pragma unroll
    for (int f = 0; f < NF; ++f) { ssum[f] = 0.f; ssq[f] = 0.f; }

    const int MT = (M + 63) >> 6;

    bf16x8 ldA[KSTEPS], ldB[KSTEPS];
    {
        int rr = mt * 64 + wave * 16 + (l & 15);
        int rc = rr < M ? rr : M - 1;
        loadA<MODE, KSTEPS, KACT>(Ap, rc, kg, ldA);
    }

    int pbuf = 0;
    for (; mt < MT; mt += bstep) {
        const int nxt = mt + bstep;
        if (nxt < MT) {
            int rr = nxt * 64 + wave * 16 + (l & 15);
            int rc = rr < M ? rr : M - 1;
            loadA<MODE, KSTEPS, KACT>(Ap, rc, kg, ldB);
        }

        if (MODE == 2) {
            #pragma unroll
            for (int ks = 0; ks < KSTEPS; ++ks) {
                f32x4 s0 = *(const f32x4*)&s_sc[ks * 32 + kg];
                f32x4 s1 = *(const f32x4*)&s_sc[ks * 32 + kg + 4];
                f32x4 h0 = *(const f32x4*)&s_sh[ks * 32 + kg];
                f32x4 h1 = *(const f32x4*)&s_sh[ks * 32 + kg + 4];
                float sv[8] = {s0.x, s0.y, s0.z, s0.w, s1.x, s1.y, s1.z, s1.w};
                float hv[8] = {h0.x, h0.y, h0.z, h0.w, h1.x, h1.y, h1.z, h1.w};
                #pragma unroll
                for (int j = 0; j < 8; ++j) {
                    float v = fmaxf(b2f(ldA[ks][j]) * sv[j] + hv[j], 0.f);
                    ldA[ks][j] = (short)f2b(v);
                }
            }
        }

        f32x4 acc[NF];
        #pragma unroll
        for (int f = 0; f < NF; ++f) acc[f] = (f32x4){0.f, 0.f, 0.f, 0.f};
        #pragma unroll
        for (int ks = 0; ks < KSTEPS; ++ks)
            #pragma unroll
            for (int f = 0; f < NF; ++f)
                acc[f] = __builtin_amdgcn_mfma_f32_16x16x32_bf16(ldA[ks], bfr[ks][f], acc[f], 0, 0, 0);

        const int rtile = mt * 64;
        char* sb = sOut[pbuf];
        #pragma unroll
        for (int f = 0; f < NF; ++f) {
            const int cl = f * 16 + (l & 15);
            #pragma unroll
            for (int j = 0; j < 4; ++j) {
                const int rl = wave * 16 + (l >> 4) * 4 + j;
                float v = acc[f][j] + bb[f];
                if (OUT_BF16) ((unsigned short*)sb)[rl * RSTRIDE + cl] = f2b(v);
                else          ((float*)sb)[rl * RSTRIDE + cl] = v;
                if (STATS && rtile + rl < M) { ssum[f] += v; ssq[f] += v * v; }
            }
        }
        __syncthreads();

        const int rmax = M - rtile;
        #pragma unroll
        for (int i = 0; i < CHUNKS / 256; ++i) {
            int c = i * 256 + tid;
            int row = c / CPR;
            int off = (c % CPR) * 16;
            if (row < rmax) {
                f32x4 v = *(const f32x4*)(sb + row * (RSTRIDE * ESZ) + off);
                char* gp = (char*)outp + ((long)(rtile + row) * NCtot + col0) * ESZ + off;
                *(f32x4*)gp = v;
            }
        }
        pbuf ^= 1;

        #pragma unroll
        for (int ks = 0; ks < KSTEPS; ++ks) ldA[ks] = ldB[ks];
    }

    if (STATS) {
        #pragma unroll
        for (int f = 0; f < NF; ++f) {
            float s = ssum[f], q = ssq[f];
            s += __shfl_xor(s, 16); s += __shfl_xor(s, 32);
            q += __shfl_xor(q, 16); q += __shfl_xor(q, 32);
            if (l < 16) {
                atomicAdd(&s_ps[f * 16 + l], s);
                atomicAdd(&s_ps[NCb + f * 16 + l], q);
            }
        }
        __syncthreads();
        float* pb = partial + (long)blockIdx.x * 2 * NCb;
        for (int i = tid; i < 2 * NCb; i += 256) pb[i] = s_ps[i];
    }
}

// ---------------- BN finalize from per-block partials ----------------
__global__ __launch_bounds__(64) void bn_finalize_p(
    const float* __restrict__ partial, int nblk, int ncb, int halves,
    const float* __restrict__ gamma, const float* __restrict__ beta,
    float invN, float* __restrict__ sc, float* __restrict__ sh)
{
    const int c = blockIdx.x;
    const int t = threadIdx.x;
    float s = 0.f, q = 0.f;
    for (int b = t; b < nblk; b += 64) {
        int half = (halves == 2) ? ((b >> 3) & 1) : 0;
        if (c / ncb != half) continue;
        const float* pb = partial + (long)b * 2 * ncb;
        s += pb[c % ncb];
        q += pb[ncb + c % ncb];
    }
    #pragma unroll
    for (int off = 1; off < 64; off <<= 1) {
        s += __shfl_xor(s, off);
        q += __shfl_xor(q, off);
    }
    if (t == 0) {
        float m = s * invN;
        float v = q * invN - m * m;
        float g = gamma[c] * rsqrtf(v + 1e-5f);
        sc[c] = g;
        sh[c] = beta[c] - m * g;
    }
}

// ---------------- pooling (bf16 h, 2 ch/lane dword loads) ----------------
__global__ __launch_bounds__(64) void pool_kernel(
    const unsigned short* __restrict__ h,
    const float* __restrict__ sc, const float* __restrict__ sh,
    const void* __restrict__ batchp, const int* __restrict__ flag,
    int Nn, float* __restrict__ out)
{
    const int g = blockIdx.x;
    const int t = threadIdx.x;
    const int d0 = t * 2;
    const int is64 = *flag;
    int lo = 0, hi = Nn;
    while (lo < hi) { int mid = (lo + hi) >> 1; if (getIdx(batchp, mid, is64) < g) lo = mid + 1; else hi = mid; }
    const int s0 = lo;
    hi = Nn;
    while (lo < hi) { int mid = (lo + hi) >> 1; if (getIdx(batchp, mid, is64) < g + 1) lo = mid + 1; else hi = mid; }
    const int s1 = lo;
    float a0 = 0.f, a1 = 0.f;
    for (int r = s0; r < s1; ++r) {
        unsigned v = *(const unsigned*)(h + (long)r * DD + d0);
        a0 += b2f((short)(v & 0xffff));
        a1 += b2f((short)(v >> 16));
    }
    const int cnt = s1 - s0;
    f32x2 o; o.x = 0.f; o.y = 0.f;
    if (cnt > 0) {
        float inv = 1.f / (float)cnt;
        o.x = a0 * inv * sc[d0] + sh[d0];
        o.y = a1 * inv * sc[d0 + 1] + sh[d0 + 1];
    }
    *(f32x2*)(out + (long)g * DD + d0) = o;
}

// ---------------- launch ----------------
extern "C" void kernel_launch(void* const* d_in, const int* in_sizes, int n_in,
                              void* d_out, int out_size, void* d_ws, size_t ws_size,
                              hipStream_t stream)
{
    const float* x     = (const float*)d_in[0];
    const float* ea    = (const float*)d_in[1];
    const float* embW  = (const float*)d_in[2];
    const float* embB  = (const float*)d_in[3];
    const float* bondW = (const float*)d_in[4];
    const float* bondB = (const float*)d_in[5];
    const float* W1    = (const float*)d_in[6];
    const float* b1    = (const float*)d_in[7];
    const float* g1    = (const float*)d_in[8];
    const float* be1   = (const float*)d_in[9];
    const float* W2    = (const float*)d_in[10];
    const float* b2    = (const float*)d_in[11];
    const float* gout  = (const float*)d_in[12];
    const float* bout  = (const float*)d_in[13];
    const void*  eidx  = d_in[14];
    const void*  batch = d_in[15];
    float* out = (float*)d_out;

    char* w = (char*)d_ws;
    unsigned short* h   = (unsigned short*)w;   w += (long)NN * DD * 2;        // 25.6MB
    unsigned short* s   = (unsigned short*)w;   w += (long)NN * DD * 2;        // 25.6MB
    unsigned short* z1  = (unsigned short*)w;   w += (long)NN * 256 * 2;       // 51.2MB
    float* eas  = (float*)w;                    w += (long)EE * EAP * 4;       // 19.2MB
    int* src_sorted = (int*)w;                  w += (long)EE * 4;             // 1.6MB
    int* row_ptr    = (int*)w;                  w += (long)(NN + 1) * 4;
    int* counts     = (int*)w;                  w += (long)NN * 4;   // zeroed together:
    int* cursor     = (int*)w;                  w += (long)NN * 4;   // [counts|cursor]
    int* tmp        = (int*)w;                  w += (long)NN * 4;
    int* bsum       = (int*)w;                  w += 1024 * 4;
    int* bsumx      = (int*)w;                  w += 1024 * 4;
    float* partial  = (float*)w;                w += (long)GEMM_GRID * 512 * 4; // 1MB
    float* sc1  = (float*)w;                    w += 256 * 4;
    float* sh1  = (float*)w;                    w += 256 * 4;
    float* sc2  = (float*)w;                    w += 128 * 4;
    float* sh2  = (float*)w;                    w += 128 * 4;
    unsigned short* embWf = (unsigned short*)w; w += 4 * 8  * 64 * 8 * 2;
    unsigned short* W1f   = (unsigned short*)w; w += 3L * 4 * 16 * 64 * 8 * 2;
    unsigned short* W2f   = (unsigned short*)w; w += 3L * 8 * 8  * 64 * 8 * 2;
    int* flag = (int*)w;

    // one memset covers counts + cursor
    hipMemsetAsync(counts, 0, (size_t)2 * NN * 4, stream);

    detect64_kernel<<<1, 256, 0, stream>>>(eidx, 256, flag);
    pack_all<<<(2048 + 6 * 4096 + 255) / 256, 256, 0, stream>>>(embW, W1, W2, embWf, W1f, W2f);

    // counting sort of edges by dst -> CSR
    const int eblocks = (EE + 255) / 256;
    const int nb = (NN + 255) / 256;
    hist_kernel<<<eblocks, 256, 0, stream>>>(eidx, flag, counts);
    scan1_kernel<<<nb, 256, 0, stream>>>(counts, tmp, bsum, NN);
    scan2_kernel<<<1, 512, 0, stream>>>(bsum, bsumx, nb);
    scan3_kernel<<<nb, 256, 0, stream>>>(tmp, bsumx, row_ptr, NN);
    scatter_kernel<<<eblocks, 256, 0, stream>>>(eidx, flag, ea, row_ptr, cursor, src_sorted, eas);

    // h0 = bf16(x @ embW + embB)   (f32 x read directly, zero-padded to K=128)
    gemm_reg<8, 4, 1, 1, true, false, ATOM_DIM><<<GEMM_GRID, 256, 0, stream>>>(
        x, nullptr, nullptr, embWf, embB, h, nullptr, NN);

    const float* scin = nullptr;
    const float* shin = nullptr;

    for (int i = 0; i < 3; ++i) {
        // s = bf16( t + sum relu(t[src] + bond) ),  t = bn_relu(h) applied inline
        msg_csr_kernel<<<4096, 256, 0, stream>>>(
            h, scin, shin, src_sorted, row_ptr, eas,
            bondW + (long)i * BOND_DIM * DD, bondB + (long)i * DD, s);

        // z1 = s @ W1 + b1   (bf16 out, per-block stats)
        gemm_reg<8, 4, 2, 0, true, true><<<GEMM_GRID, 256, 0, stream>>>(
            s, nullptr, nullptr, W1f + (long)i * 4 * 16 * 64 * 8,
            b1 + (long)i * 256, z1, partial, NN);
        bn_finalize_p<<<256, 64, 0, stream>>>(partial, GEMM_GRID, 128, 2,
            g1 + (long)i * 256, be1 + (long)i * 256, 1.f / NN, sc1, sh1);

        // h = bf16(relu(bn(z1)) @ W2 + b2)   (stats on f32 pre-round)
        gemm_reg<4, 8, 2, 2, true, true><<<GEMM_GRID, 256, 0, stream>>>(
            z1, sc1, sh1, W2f + (long)i * 8 * 8 * 64 * 8,
            b2 + (long)i * DD, h, partial, NN);
        bn_finalize_p<<<128, 64, 0, stream>>>(partial, GEMM_GRID, 64, 2,
            gout + (long)i * DD, bout + (long)i * DD, 1.f / NN, sc2, sh2);

        scin = sc2; shin = sh2;
    }

    pool_kernel<<<GG, 64, 0, stream>>>(h, sc2, sh2, batch, flag, NN, out);
}